// Round 11
// baseline (127.571 us; speedup 1.0000x reference)
//
#include <hip/hip_runtime.h>
#include <math.h>

#define CLS   4096      // row length C
#define KSEL  2048u     // k = round(C * 0.5)
#define TPB   256
#define NBLK  768       // persistent grid: 3 blocks/CU x 256 CU

typedef float f32x4 __attribute__((ext_vector_type(4)));

// LDS layout (bytes), total 43072:
//  buf  : 32768 @ 0       staging for ONE row (token 16K | proxy 16K), DMA-filled
//  h0   : u32[2048] @ 32768 (8192)   12-bit hist, single copy
//  cand : u32[512]  @ 40960 (2048)   boundary-bin candidates
//  s_cnt @43008 ; s_wt[4] @43012 ; s_bc[3] @43028 ; s_fr f32[8] @43040 -> 43072
//  zero-per-row = h0+cand+s_cnt
//  fallback aliases (h0 region, h0 dead): s_flag u8[4096]@32768 ; s_suf u32[256]@36864 ;
//    h1 u32[260]@37888 ; h2 u32[260]@38928 ; h3 u32[64]@39968
//
// Pipeline per row: ds_read row r -> barrier -> issue 8 global_load_lds (row r+1)
// -> selection chain (5 raw barriers, lgkmcnt only) -> stores -> zero ->
// vmcnt(4)+lgkmcnt(0) -> barrier. DMA for r+1 hides under r's selection.
// Raw s_barrier (not __syncthreads) so the compiler doesn't drain vmcnt at
// every barrier (m97 barrier-drain trap).

#define BARRIER_LGKM() do { \
    asm volatile("s_waitcnt lgkmcnt(0)" ::: "memory"); \
    __builtin_amdgcn_s_barrier(); } while (0)

__device__ __forceinline__ void gl_lds16(const float* g, void* l) {
    __builtin_amdgcn_global_load_lds(
        (const __attribute__((address_space(1))) unsigned int*)g,
        (__attribute__((address_space(3))) unsigned int*)l,
        16, 0, 0);
}

template<int SHIFT, int NBITS, int BPL>
__device__ __forceinline__ void radix_small(const float sc[16], unsigned* hist,
        int lane, unsigned& prefix, unsigned& kr, unsigned& cnt_eq)
{
    const unsigned msk = (1u << NBITS) - 1u;
    #pragma unroll
    for (int i = 0; i < 16; ++i) {
        unsigned u = __float_as_uint(sc[i]);
        if ((u >> (SHIFT + NBITS)) == (prefix >> (SHIFT + NBITS)))
            atomicAdd(&hist[(u >> SHIFT) & msk], 1u);
    }
    __syncthreads();
    unsigned c[BPL];
    if constexpr (BPL == 4) {
        uint4 x = *(const uint4*)&hist[lane * 4];
        c[0] = x.x; c[1] = x.y; c[2] = x.z; c[3] = x.w;
    } else {
        c[0] = hist[lane];
    }
    unsigned sfx[BPL + 1]; sfx[BPL] = 0;
    #pragma unroll
    for (int j = BPL - 1; j >= 0; --j) sfx[j] = sfx[j + 1] + c[j];
    const unsigned tot = sfx[0];
    unsigned s = tot;
    #pragma unroll
    for (int off = 1; off < 64; off <<= 1) {
        unsigned t = __shfl_down(s, off);
        if (lane + off < 64) s += t;
    }
    const unsigned Sx = s - tot;
    const bool has = (Sx < kr) && (kr <= Sx + tot);
    unsigned bin = 0, below = 0, ceq = 0;
    if (has) {
        #pragma unroll
        for (int j = 0; j < BPL; ++j)
            if (Sx + sfx[j] >= kr && Sx + sfx[j + 1] < kr) {
                bin = (unsigned)(lane * BPL + j);
                below = Sx + sfx[j + 1];
                ceq = c[j];
            }
    }
    unsigned long long m = __ballot(has);
    int src = (int)__builtin_ctzll(m);
    bin = __shfl(bin, src); below = __shfl(below, src); ceq = __shfl(ceq, src);
    prefix |= bin << SHIFT;
    kr -= below;
    cnt_eq = ceq;
}

__global__ __launch_bounds__(TPB) void proxy_gate_kernel(
    const float* __restrict__ token,
    const float* __restrict__ proxy,
    float* __restrict__ out,
    int nrows, int rpb)
{
    __shared__ __align__(16) unsigned char lds[43072];
    unsigned* h0    = (unsigned*)(lds + 32768);
    unsigned* cand  = (unsigned*)(lds + 40960);
    unsigned* s_cnt = (unsigned*)(lds + 43008);
    unsigned* s_wt  = (unsigned*)(lds + 43012);
    unsigned* s_bc  = (unsigned*)(lds + 43028);
    float*    s_fr  = (float*)   (lds + 43040);
    unsigned char* s_flag = lds + 32768;            // fallback aliases (h0 dead)
    unsigned*      s_suf  = (unsigned*)(lds + 36864);
    unsigned*      h1     = (unsigned*)(lds + 37888);
    unsigned*      h2     = (unsigned*)(lds + 38928);
    unsigned*      h3     = (unsigned*)(lds + 39968);

    const int tid  = threadIdx.x;
    const int lane = tid & 63;
    const int wv   = tid >> 6;
    const int r0   = blockIdx.x * rpb;
    if (r0 >= nrows) return;
    const int r1   = (r0 + rpb < nrows) ? (r0 + rpb) : nrows;

    // ---- prologue: DMA row r0 into buf; zero h0/cand; drain; barrier ----
    {
        const float* tg = token + (size_t)r0 * CLS;
        const float* pg = proxy + (size_t)r0 * CLS;
        #pragma unroll
        for (int i = 0; i < 4; ++i) {
            gl_lds16(tg + i*1024 + tid*4, lds +         i*4096 + wv*1024);
            gl_lds16(pg + i*1024 + tid*4, lds + 16384 + i*4096 + wv*1024);
        }
        uint4 z = make_uint4(0u, 0u, 0u, 0u);
        uint4* zp = (uint4*)(lds + 32768);
        #pragma unroll
        for (int m = 0; m < 3; ++m) { int idx = m*TPB + tid; if (idx < 640) zp[idx] = z; }
        if (tid == 0) *s_cnt = 0u;
        asm volatile("s_waitcnt vmcnt(0) lgkmcnt(0)" ::: "memory");
        __builtin_amdgcn_s_barrier();
    }

    for (int row = r0; row < r1; ++row) {
        // ---- read row from LDS staging into registers ----
        float4 tv[4]; float sc[16];
        float sum = 0.f, sumsq = 0.f;
        #pragma unroll
        for (int i = 0; i < 4; ++i) {
            float4 t = *(const float4*)(lds +         i*4096 + tid*16);
            float4 p = *(const float4*)(lds + 16384 + i*4096 + tid*16);
            tv[i] = t;
            float a;
            a = fabsf(t.x*p.x); sc[i*4+0]=a; sum+=a; sumsq+=a*a;
            a = fabsf(t.y*p.y); sc[i*4+1]=a; sum+=a; sumsq+=a*a;
            a = fabsf(t.z*p.z); sc[i*4+2]=a; sum+=a; sumsq+=a*a;
            a = fabsf(t.w*p.w); sc[i*4+3]=a; sum+=a; sumsq+=a*a;
        }
        BARRIER_LGKM();                              // Ba: all waves done reading buf

        // ---- issue DMA for next row; streams under the selection chain ----
        if (row + 1 < r1) {
            const float* tg = token + (size_t)(row+1) * CLS;
            const float* pg = proxy + (size_t)(row+1) * CLS;
            #pragma unroll
            for (int i = 0; i < 4; ++i) {
                gl_lds16(tg + i*1024 + tid*4, lds +         i*4096 + wv*1024);
                gl_lds16(pg + i*1024 + tid*4, lds + 16384 + i*4096 + wv*1024);
            }
        }

        // ---- pass 0 atomics (12-bit bins) + stats reduce ----
        #pragma unroll
        for (int i = 0; i < 16; ++i)
            atomicAdd(&h0[__float_as_uint(sc[i]) >> 20], 1u);
        #pragma unroll
        for (int off = 32; off > 0; off >>= 1) {
            sum   += __shfl_xor(sum, off);
            sumsq += __shfl_xor(sumsq, off);
        }
        if (lane == 0) { s_fr[wv] = sum; s_fr[4+wv] = sumsq; }
        BARRIER_LGKM();                              // B1

        const float tot_s = s_fr[0]+s_fr[1]+s_fr[2]+s_fr[3];
        const float tot_q = s_fr[4]+s_fr[5]+s_fr[6]+s_fr[7];
        const float mu = tot_s * (1.0f/CLS);
        float var = (tot_q - tot_s*mu) * (1.0f/(CLS-1));
        var = fmaxf(var, 0.0f);
        const float inv_sigma = 1.0f / fmaxf(sqrtf(var), 1e-6f);

        // ---- pass 0 scan: thread t owns bins [8t,8t+8) ----
        unsigned kr = KSEL;
        {
            uint4 x0 = *(const uint4*)&h0[tid*8];
            uint4 x1 = *(const uint4*)&h0[tid*8 + 4];
            unsigned c[8] = { x0.x, x0.y, x0.z, x0.w, x1.x, x1.y, x1.z, x1.w };
            unsigned sfx[9]; sfx[8] = 0;
            #pragma unroll
            for (int j = 7; j >= 0; --j) sfx[j] = sfx[j+1] + c[j];
            const unsigned tot = sfx[0];
            unsigned s = tot;
            #pragma unroll
            for (int off = 1; off < 64; off <<= 1) {
                unsigned t = __shfl_down(s, off);
                if (lane + off < 64) s += t;
            }
            if (lane == 0) s_wt[wv] = s;
            BARRIER_LGKM();                          // B2
            unsigned addhi = 0;
            #pragma unroll
            for (int w2 = 0; w2 < 4; ++w2) if (w2 > wv) addhi += s_wt[w2];
            const unsigned Sx = (s - tot) + addhi;
            if (Sx < kr && kr <= Sx + tot) {
                #pragma unroll
                for (int j = 0; j < 8; ++j)
                    if (Sx + sfx[j] >= kr && Sx + sfx[j+1] < kr) {
                        s_bc[0] = (unsigned)(tid*8 + j);
                        s_bc[1] = Sx + sfx[j+1];
                        s_bc[2] = c[j];
                    }
            }
            BARRIER_LGKM();                          // B3
            kr -= s_bc[1];
        }
        const unsigned bin = s_bc[0];
        unsigned cnt_eq = s_bc[2];

        // ---- gather boundary-bin candidates: key=(u<<12)|(4095-idx) ----
        {
            unsigned cmask = 0, lc = 0;
            #pragma unroll
            for (int ii = 0; ii < 16; ++ii) {
                bool cnd = ((__float_as_uint(sc[ii]) >> 20) == bin);
                cmask |= ((unsigned)cnd) << ii;
                lc += (unsigned)cnd;
            }
            unsigned inc = lc;
            #pragma unroll
            for (int off = 1; off < 64; off <<= 1) {
                unsigned t = __shfl_up(inc, off);
                if (lane >= off) inc += t;
            }
            const unsigned wtot = __shfl(inc, 63);
            unsigned wbase = 0;
            if (lane == 0) wbase = atomicAdd(s_cnt, wtot);
            wbase = __shfl(wbase, 0);
            unsigned p = wbase + (inc - lc);
            #pragma unroll
            for (int ii = 0; ii < 16; ++ii) {
                if ((cmask >> ii) & 1u) {
                    unsigned u = __float_as_uint(sc[ii]);
                    unsigned idx = (unsigned)((ii >> 2)*1024 + tid*4 + (ii & 3));
                    if (p < 512u) cand[p] = (u << 12) | (4095u - idx);
                    ++p;
                }
            }
        }
        BARRIER_LGKM();                              // B4
        const unsigned cnt = *s_cnt;
        const bool cand_mode = (cnt <= 512u);

        float thr = 0.f; bool tie_rare = false;
        if (cand_mode) {
            #pragma unroll
            for (int rpt = 0; rpt < 2; ++rpt) {
                const unsigned slot = (unsigned)tid + (unsigned)rpt*256u;
                if (slot < cnt) {
                    const unsigned my = cand[slot];
                    unsigned rank = 0;
                    const uint4* c4 = (const uint4*)cand;
                    const unsigned nq = (cnt + 3u) >> 2;
                    for (unsigned q = 0; q < nq; ++q) {
                        uint4 v = c4[q];
                        rank += (unsigned)(v.x > my) + (unsigned)(v.y > my)
                              + (unsigned)(v.z > my) + (unsigned)(v.w > my);
                    }
                    if (rank == kr - 1u) s_bc[0] = my;
                }
            }
        } else {
            // ---- rare fallback (cnt>512); __syncthreads ok here (never taken) ----
            unsigned prefix = bin << 20;
            {
                unsigned* hz = (unsigned*)(lds + 37888);
                #pragma unroll
                for (int m = 0; m < 3; ++m) { int ix = m*TPB + tid; if (ix < 584) hz[ix] = 0u; }
            }
            __syncthreads();
            radix_small<12, 8, 4>(sc, h1, lane, prefix, kr, cnt_eq);
            radix_small< 4, 8, 4>(sc, h2, lane, prefix, kr, cnt_eq);
            radix_small< 0, 4, 1>(sc, h3, lane, prefix, kr, cnt_eq);
            thr = __uint_as_float(prefix);
            tie_rare = (cnt_eq != kr);
            if (tie_rare) {
                #pragma unroll
                for (int i = 0; i < 4; ++i)
                    #pragma unroll
                    for (int c2 = 0; c2 < 4; ++c2)
                        s_flag[i*1024 + tid*4 + c2] = (sc[i*4+c2] == thr) ? 1 : 0;
                __syncthreads();
                unsigned lc = 0;
                unsigned char mf[16];
                #pragma unroll
                for (int m = 0; m < 16; ++m) { mf[m] = s_flag[tid*16 + m]; lc += mf[m]; }
                s_suf[tid] = lc;
                __syncthreads();
                #pragma unroll
                for (int off = 1; off < 256; off <<= 1) {
                    unsigned w = s_suf[tid] + ((tid >= off) ? s_suf[tid - off] : 0u);
                    __syncthreads();
                    s_suf[tid] = w;
                    __syncthreads();
                }
                unsigned r2 = s_suf[tid] - lc;
                #pragma unroll
                for (int m = 0; m < 16; ++m) {
                    if (mf[m]) { s_flag[tid*16 + m] = (r2 < kr) ? 2 : 0; ++r2; }
                }
            }
        }
        BARRIER_LGKM();                              // B5: Kth / flags visible
        const unsigned long long Kth64 =
            ((unsigned long long)bin << 32) | (unsigned long long)s_bc[0];

        // ---- gate + store ----
        f32x4* o4 = (f32x4*)(out + (size_t)row * CLS);
        const float A  = -inv_sigma * 1.44269504f;   // exp(-z) = 2^(s*A + Bc)
        const float Bc = -mu * A;
        const unsigned rbase = 1023u - 4u*(unsigned)tid;
        #pragma unroll
        for (int i = 0; i < 4; ++i) {
            const float tkc[4] = { tv[i].x, tv[i].y, tv[i].z, tv[i].w };
            f32x4 rv;
            #pragma unroll
            for (int c2 = 0; c2 < 4; ++c2) {
                const float s = sc[i*4+c2];
                const float e2 = __builtin_amdgcn_exp2f(fmaf(s, A, Bc));
                const float soft = __builtin_amdgcn_rcpf(1.0f + e2);
                const unsigned u = __float_as_uint(s);
                bool hard;
                if (cand_mode) {
                    const unsigned long long key =
                        ((unsigned long long)(u >> 20) << 32)
                        | (unsigned long long)((u << 12) | (rbase + (3u-(unsigned)i)*1024u - (unsigned)c2));
                    hard = (key >= Kth64);
                } else if (tie_rare) {
                    hard = (s > thr) || ((s == thr) && (s_flag[i*1024 + tid*4 + c2] == 2));
                } else {
                    hard = (s >= thr);
                }
                rv[c2] = tkc[c2] * (hard ? 1.0f : soft);
            }
            __builtin_nontemporal_store(rv, &o4[i*TPB + tid]);
        }

        if (!cand_mode) { BARRIER_LGKM(); }          // rare: protect s_flag vs zeroing

        // ---- zero h0/cand/s_cnt for next row; drain DMA (not stores); barrier ----
        {
            uint4 z = make_uint4(0u, 0u, 0u, 0u);
            uint4* zp = (uint4*)(lds + 32768);
            #pragma unroll
            for (int m = 0; m < 3; ++m) { int idx = m*TPB + tid; if (idx < 640) zp[idx] = z; }
            if (tid == 0) *s_cnt = 0u;
        }
        asm volatile("s_waitcnt vmcnt(4) lgkmcnt(0)" ::: "memory");
        __builtin_amdgcn_s_barrier();                // END: next row staged + LDS zeroed
    }
}

extern "C" void kernel_launch(void* const* d_in, const int* in_sizes, int n_in,
                              void* d_out, int out_size, void* d_ws, size_t ws_size,
                              hipStream_t stream) {
    const float* token = (const float*)d_in[0];
    const float* proxy = (const float*)d_in[1];
    float* outp = (float*)d_out;
    const int B = in_sizes[0] / CLS;
    const int grid = (B < NBLK) ? B : NBLK;
    const int rpb = (B + grid - 1) / grid;
    hipLaunchKernelGGL(proxy_gate_kernel, dim3(grid), dim3(TPB), 0, stream,
                       token, proxy, outp, B, rpb);
}

// Round 12
// 73.097 us; speedup vs baseline: 1.7452x; 1.7452x over previous
//
#include <hip/hip_runtime.h>
#include <math.h>

#define CLS   4096      // row length C
#define KSEL  2048u     // k = round(C * 0.5)
#define TPB   512       // 8 elements per thread

typedef float f32x4 __attribute__((ext_vector_type(4)));

// LDS layout (bytes), total 10352:
//  h0   : u32[2048] @     0 ( 8192)  12-bit hist, single copy
//  cand : u32[512]  @  8192 ( 2048)  boundary-bin candidates (packed keys)
//  s_cnt @10240 ; s_wt u32[8] @10244 ; s_bc u32[3] @10276 ; s_fr f32[16] @10288
//  zero-per-row = [0,10240) = 640 uint4 + s_cnt (under global-load latency)
//  fallback aliases (h0/cand dead): s_flag u8[4096]@0 ; s_suf u32[512]@4096 ;
//    h1 u32[260]@6144 ; h2 u32[260]@7200 ; h3 u32[64]@8256
// element index: elem(i,t,c) = i*2048 + t*4 + c, i in {0,1}, c in {0..3}

template<int SHIFT, int NBITS, int BPL>
__device__ __forceinline__ void radix_small(const float sc[8], unsigned* hist,
        int lane, unsigned& prefix, unsigned& kr, unsigned& cnt_eq)
{
    const unsigned msk = (1u << NBITS) - 1u;
    #pragma unroll
    for (int i = 0; i < 8; ++i) {
        unsigned u = __float_as_uint(sc[i]);
        if ((u >> (SHIFT + NBITS)) == (prefix >> (SHIFT + NBITS)))
            atomicAdd(&hist[(u >> SHIFT) & msk], 1u);
    }
    __syncthreads();
    unsigned c[BPL];
    if constexpr (BPL == 4) {
        uint4 x = *(const uint4*)&hist[lane * 4];
        c[0] = x.x; c[1] = x.y; c[2] = x.z; c[3] = x.w;
    } else {
        c[0] = hist[lane];
    }
    unsigned sfx[BPL + 1]; sfx[BPL] = 0;
    #pragma unroll
    for (int j = BPL - 1; j >= 0; --j) sfx[j] = sfx[j + 1] + c[j];
    const unsigned tot = sfx[0];
    unsigned s = tot;
    #pragma unroll
    for (int off = 1; off < 64; off <<= 1) {
        unsigned t = __shfl_down(s, off);
        if (lane + off < 64) s += t;
    }
    const unsigned Sx = s - tot;
    const bool has = (Sx < kr) && (kr <= Sx + tot);
    unsigned bin = 0, below = 0, ceq = 0;
    if (has) {
        #pragma unroll
        for (int j = 0; j < BPL; ++j)
            if (Sx + sfx[j] >= kr && Sx + sfx[j + 1] < kr) {
                bin = (unsigned)(lane * BPL + j);
                below = Sx + sfx[j + 1];
                ceq = c[j];
            }
    }
    unsigned long long m = __ballot(has);
    int src = (int)__builtin_ctzll(m);
    bin = __shfl(bin, src); below = __shfl(below, src); ceq = __shfl(ceq, src);
    prefix |= bin << SHIFT;
    kr -= below;
    cnt_eq = ceq;
}

__global__ __launch_bounds__(TPB) void proxy_gate_kernel(
    const float* __restrict__ token,
    const float* __restrict__ proxy,
    float* __restrict__ out)
{
    __shared__ __align__(16) unsigned char lds[10352];
    unsigned* h0    = (unsigned*)(lds);
    unsigned* cand  = (unsigned*)(lds + 8192);
    unsigned* s_cnt = (unsigned*)(lds + 10240);
    unsigned* s_wt  = (unsigned*)(lds + 10244);
    unsigned* s_bc  = (unsigned*)(lds + 10276);
    float*    s_fr  = (float*)   (lds + 10288);
    unsigned char* s_flag = lds;                    // fallback aliases (h0 dead)
    unsigned*      s_suf  = (unsigned*)(lds + 4096);
    unsigned*      h1     = (unsigned*)(lds + 6144);
    unsigned*      h2     = (unsigned*)(lds + 7200);
    unsigned*      h3     = (unsigned*)(lds + 8256);

    const int tid  = threadIdx.x;
    const int lane = tid & 63;
    const int wv   = tid >> 6;                      // 8 waves
    const size_t base = (size_t)blockIdx.x * CLS;
    const float4* t4 = (const float4*)(token + base);
    const float4* p4 = (const float4*)(proxy + base);
    f32x4* o4 = (f32x4*)(out + base);

    // ---- issue all global loads; zero h0+cand (+s_cnt) under their latency ----
    float4 tv[2], pv[2];
    #pragma unroll
    for (int i = 0; i < 2; ++i) { tv[i] = t4[i*TPB + tid]; pv[i] = p4[i*TPB + tid]; }
    {
        uint4 z = make_uint4(0u, 0u, 0u, 0u);
        uint4* zp = (uint4*)lds;
        #pragma unroll
        for (int m = 0; m < 2; ++m) { int idx = m*TPB + tid; if (idx < 640) zp[idx] = z; }
        if (tid == 0) *s_cnt = 0u;
    }

    float sc[8];
    float sum = 0.f, sumsq = 0.f;
    #pragma unroll
    for (int i = 0; i < 2; ++i) {
        float a;
        a = fabsf(tv[i].x*pv[i].x); sc[i*4+0]=a; sum+=a; sumsq+=a*a;
        a = fabsf(tv[i].y*pv[i].y); sc[i*4+1]=a; sum+=a; sumsq+=a*a;
        a = fabsf(tv[i].z*pv[i].z); sc[i*4+2]=a; sum+=a; sumsq+=a*a;
        a = fabsf(tv[i].w*pv[i].w); sc[i*4+3]=a; sum+=a; sumsq+=a*a;
    }
    __syncthreads();                                 // B0: zeroing visible

    // ---- pass 0 atomics (12-bit bins) + stats reduce ----
    #pragma unroll
    for (int i = 0; i < 8; ++i)
        atomicAdd(&h0[__float_as_uint(sc[i]) >> 20], 1u);
    #pragma unroll
    for (int off = 32; off > 0; off >>= 1) {
        sum   += __shfl_xor(sum, off);
        sumsq += __shfl_xor(sumsq, off);
    }
    if (lane == 0) { s_fr[wv] = sum; s_fr[8+wv] = sumsq; }
    __syncthreads();                                 // B1: atomics + stats visible

    float tot_s = 0.f, tot_q = 0.f;
    #pragma unroll
    for (int w = 0; w < 8; ++w) { tot_s += s_fr[w]; tot_q += s_fr[8+w]; }
    const float mu = tot_s * (1.0f/CLS);
    float var = (tot_q - tot_s*mu) * (1.0f/(CLS-1));
    var = fmaxf(var, 0.0f);
    const float inv_sigma = 1.0f / fmaxf(sqrtf(var), 1e-6f);

    // ---- pass 0 scan: thread t owns bins [4t,4t+4), one uint4 read ----
    unsigned kr = KSEL;
    {
        uint4 x0 = *(const uint4*)&h0[tid*4];
        unsigned c[4] = { x0.x, x0.y, x0.z, x0.w };
        unsigned sfx[5]; sfx[4] = 0;
        #pragma unroll
        for (int j = 3; j >= 0; --j) sfx[j] = sfx[j+1] + c[j];
        const unsigned tot = sfx[0];
        unsigned s = tot;
        #pragma unroll
        for (int off = 1; off < 64; off <<= 1) {
            unsigned t = __shfl_down(s, off);
            if (lane + off < 64) s += t;
        }
        if (lane == 0) s_wt[wv] = s;
        __syncthreads();                             // B2
        unsigned addhi = 0;
        #pragma unroll
        for (int w2 = 0; w2 < 8; ++w2) if (w2 > wv) addhi += s_wt[w2];
        const unsigned Sx = (s - tot) + addhi;
        if (Sx < kr && kr <= Sx + tot) {
            #pragma unroll
            for (int j = 0; j < 4; ++j)
                if (Sx + sfx[j] >= kr && Sx + sfx[j+1] < kr) {
                    s_bc[0] = (unsigned)(tid*4 + j);
                    s_bc[1] = Sx + sfx[j+1];
                    s_bc[2] = c[j];
                }
        }
        __syncthreads();                             // B3
        kr -= s_bc[1];
    }
    const unsigned bin = s_bc[0];
    unsigned cnt_eq = s_bc[2];

    // ---- gather boundary-bin candidates: key=(u<<12)|(4095-idx), distinct ----
    {
        unsigned cmask = 0, lc = 0;
        #pragma unroll
        for (int ii = 0; ii < 8; ++ii) {
            bool cnd = ((__float_as_uint(sc[ii]) >> 20) == bin);
            cmask |= ((unsigned)cnd) << ii;
            lc += (unsigned)cnd;
        }
        unsigned inc = lc;
        #pragma unroll
        for (int off = 1; off < 64; off <<= 1) {
            unsigned t = __shfl_up(inc, off);
            if (lane >= off) inc += t;
        }
        const unsigned wtot = __shfl(inc, 63);
        unsigned wbase = 0;
        if (lane == 0) wbase = atomicAdd(s_cnt, wtot);
        wbase = __shfl(wbase, 0);
        unsigned p = wbase + (inc - lc);
        #pragma unroll
        for (int ii = 0; ii < 8; ++ii) {
            if ((cmask >> ii) & 1u) {
                unsigned u = __float_as_uint(sc[ii]);
                unsigned idx = (unsigned)((ii >> 2)*2048 + tid*4 + (ii & 3));
                if (p < 512u) cand[p] = (u << 12) | (4095u - idx);
                ++p;
            }
        }
    }
    __syncthreads();                                 // B4
    const unsigned cnt = *s_cnt;
    const bool cand_mode = (cnt <= 512u);

    float thr = 0.f; bool tie_rare = false;
    if (cand_mode) {
        // ---- cooperative rank: thread tid handles cand slot tid ----
        if ((unsigned)tid < cnt) {
            const unsigned my = cand[tid];
            unsigned rank = 0;
            const uint4* c4 = (const uint4*)cand;
            const unsigned nq = (cnt + 3u) >> 2;
            for (unsigned q = 0; q < nq; ++q) {      // same-address broadcast reads
                uint4 v = c4[q];
                rank += (unsigned)(v.x > my) + (unsigned)(v.y > my)
                      + (unsigned)(v.z > my) + (unsigned)(v.w > my);
            }
            if (rank == kr - 1u) s_bc[0] = my;       // unique: keys distinct
        }
    } else {
        // ---- rare fallback (cnt>512): radix chain + stable tie ranking ----
        unsigned prefix = bin << 20;
        {
            unsigned* hz = (unsigned*)(lds + 6144);  // zero h1/h2/h3 (h0 dead)
            #pragma unroll
            for (int m = 0; m < 2; ++m) { int ix = m*TPB + tid; if (ix < 584) hz[ix] = 0u; }
        }
        __syncthreads();
        radix_small<12, 8, 4>(sc, h1, lane, prefix, kr, cnt_eq);
        radix_small< 4, 8, 4>(sc, h2, lane, prefix, kr, cnt_eq);
        radix_small< 0, 4, 1>(sc, h3, lane, prefix, kr, cnt_eq);
        thr = __uint_as_float(prefix);
        tie_rare = (cnt_eq != kr);
        if (tie_rare) {
            #pragma unroll
            for (int i = 0; i < 2; ++i)
                #pragma unroll
                for (int c2 = 0; c2 < 4; ++c2)
                    s_flag[i*2048 + tid*4 + c2] = (sc[i*4+c2] == thr) ? 1 : 0;
            __syncthreads();
            unsigned lc = 0;
            unsigned char mf[8];
            #pragma unroll
            for (int m = 0; m < 8; ++m) { mf[m] = s_flag[tid*8 + m]; lc += mf[m]; }
            s_suf[tid] = lc;
            __syncthreads();
            #pragma unroll
            for (int off = 1; off < 512; off <<= 1) {   // inclusive forward scan
                unsigned w = s_suf[tid] + ((tid >= off) ? s_suf[tid - off] : 0u);
                __syncthreads();
                s_suf[tid] = w;
                __syncthreads();
            }
            unsigned r2 = s_suf[tid] - lc;
            #pragma unroll
            for (int m = 0; m < 8; ++m) {
                if (mf[m]) { s_flag[tid*8 + m] = (r2 < kr) ? 2 : 0; ++r2; }
            }
        }
    }
    __syncthreads();                                 // B5: Kth / flags visible
    const unsigned Kth = s_bc[0];

    // ---- gate + store: sigmoid via exp2+raw rcp; hard via 32-bit compares ----
    const float A  = -inv_sigma * 1.44269504f;       // exp(-z) = 2^(s*A + Bc)
    const float Bc = -mu * A;
    const unsigned rbase = 4095u - 4u*(unsigned)tid; // 4095-idx = rbase - 2048i - c
    #pragma unroll
    for (int i = 0; i < 2; ++i) {
        const float tkc[4] = { tv[i].x, tv[i].y, tv[i].z, tv[i].w };
        f32x4 rv;
        #pragma unroll
        for (int c2 = 0; c2 < 4; ++c2) {
            const float s = sc[i*4+c2];
            const float e2 = __builtin_amdgcn_exp2f(fmaf(s, A, Bc));
            const float soft = __builtin_amdgcn_rcpf(1.0f + e2);
            const unsigned u = __float_as_uint(s);
            bool hard;
            if (cand_mode) {
                const unsigned e = u >> 20;
                const unsigned packed = (u << 12) | (rbase - 2048u*(unsigned)i - (unsigned)c2);
                hard = (e > bin) || ((e == bin) && (packed >= Kth));
            } else if (tie_rare) {
                hard = (s > thr) || ((s == thr) && (s_flag[i*2048 + tid*4 + c2] == 2));
            } else {
                hard = (s >= thr);
            }
            rv[c2] = tkc[c2] * (hard ? 1.0f : soft);
        }
        __builtin_nontemporal_store(rv, &o4[i*TPB + tid]);
    }
}

extern "C" void kernel_launch(void* const* d_in, const int* in_sizes, int n_in,
                              void* d_out, int out_size, void* d_ws, size_t ws_size,
                              hipStream_t stream) {
    const float* token = (const float*)d_in[0];
    const float* proxy = (const float*)d_in[1];
    float* outp = (float*)d_out;
    const int B = in_sizes[0] / CLS;
    hipLaunchKernelGGL(proxy_gate_kernel, dim3(B), dim3(TPB), 0, stream,
                       token, proxy, outp);
}